// Round 1
// baseline (865.506 us; speedup 1.0000x reference)
//
#include <hip/hip_runtime.h>

#define B_ 16
#define L_ 512
#define H_ 256
#define V_ 32000
#define HALF_ 128

// ---------------- embedding gather ----------------
__global__ void gather_kernel(const int* __restrict__ seq, const float* __restrict__ embed,
                              float* __restrict__ h) {
  int token = blockIdx.x;
  int lane = threadIdx.x;            // 64 threads, float4 each -> 256 floats
  int row = seq[token];
  const float4* e4 = (const float4*)(embed + (size_t)row * H_);
  float4* h4 = (float4*)(h + (size_t)token * H_);
  h4[lane] = e4[lane];
}

// ---------------- fp32 TN GEMM: C[M,N] = act(A[M,K] @ B[N,K]^T + bias + R) ----------------
template <bool RELU, bool HASBIAS, bool HASRES>
__global__ __launch_bounds__(256) void gemm_tn(const float* __restrict__ A,
                                               const float* __restrict__ Bm,
                                               const float* __restrict__ bias,
                                               const float* __restrict__ Rm,
                                               float* __restrict__ C,
                                               int M, int N, int K) {
  __shared__ float As[16][68];
  __shared__ float Bs[16][68];
  int tid = threadIdx.x;
  int bm = blockIdx.y * 64, bn = blockIdx.x * 64;
  int tx = tid & 15, ty = tid >> 4;
  int lr = tid >> 2;          // 0..63
  int lk = (tid & 3) * 4;     // 0,4,8,12
  float acc[4][4];
#pragma unroll
  for (int rr = 0; rr < 4; rr++)
#pragma unroll
    for (int cc = 0; cc < 4; cc++) acc[rr][cc] = 0.f;

  const float* Aptr = A + (size_t)(bm + lr) * K + lk;
  const float* Bptr = Bm + (size_t)(bn + lr) * K + lk;

  for (int k0 = 0; k0 < K; k0 += 16) {
    float4 a4 = *(const float4*)(Aptr + k0);
    float4 b4 = *(const float4*)(Bptr + k0);
    __syncthreads();
    As[lk + 0][lr] = a4.x; As[lk + 1][lr] = a4.y; As[lk + 2][lr] = a4.z; As[lk + 3][lr] = a4.w;
    Bs[lk + 0][lr] = b4.x; Bs[lk + 1][lr] = b4.y; Bs[lk + 2][lr] = b4.z; Bs[lk + 3][lr] = b4.w;
    __syncthreads();
#pragma unroll
    for (int kk = 0; kk < 16; kk++) {
      float4 av = *(const float4*)&As[kk][ty * 4];
      float4 bv = *(const float4*)&Bs[kk][tx * 4];
      float ar[4] = {av.x, av.y, av.z, av.w};
      float br[4] = {bv.x, bv.y, bv.z, bv.w};
#pragma unroll
      for (int rr = 0; rr < 4; rr++)
#pragma unroll
        for (int cc = 0; cc < 4; cc++) acc[rr][cc] += ar[rr] * br[cc];
    }
  }

  int col = bn + tx * 4;
  float4 bb;
  if (HASBIAS) bb = *(const float4*)(bias + col);
  else { bb.x = bb.y = bb.z = bb.w = 0.f; }
#pragma unroll
  for (int rr = 0; rr < 4; rr++) {
    int row = bm + ty * 4 + rr;
    float4 o;
    o.x = acc[rr][0] + bb.x;
    o.y = acc[rr][1] + bb.y;
    o.z = acc[rr][2] + bb.z;
    o.w = acc[rr][3] + bb.w;
    if (HASRES) {
      float4 rv = *(const float4*)(Rm + (size_t)row * N + col);
      o.x += rv.x; o.y += rv.y; o.z += rv.z; o.w += rv.w;
    }
    if (RELU) {
      o.x = fmaxf(o.x, 0.f); o.y = fmaxf(o.y, 0.f);
      o.z = fmaxf(o.z, 0.f); o.w = fmaxf(o.w, 0.f);
    }
    *(float4*)(C + (size_t)row * N + col) = o;
  }
}

// ---------------- LayerNorm over H=256, one wave per row ----------------
__global__ void ln_kernel(const float* __restrict__ x, const float* __restrict__ gamma,
                          const float* __restrict__ beta, float* __restrict__ y) {
  int row = blockIdx.x;
  int lane = threadIdx.x;  // 64
  const float4* x4 = (const float4*)(x + (size_t)row * H_);
  float4 v = x4[lane];
  float s = v.x + v.y + v.z + v.w;
  float sq = v.x * v.x + v.y * v.y + v.z * v.z + v.w * v.w;
#pragma unroll
  for (int off = 32; off >= 1; off >>= 1) {
    s += __shfl_xor(s, off);
    sq += __shfl_xor(sq, off);
  }
  float mu = s * (1.f / H_);
  float var = sq * (1.f / H_) - mu * mu;
  float inv = rsqrtf(var + 1e-5f);
  float4 g = ((const float4*)gamma)[lane];
  float4 b = ((const float4*)beta)[lane];
  float4 o;
  o.x = (v.x - mu) * inv * g.x + b.x;
  o.y = (v.y - mu) * inv * g.y + b.y;
  o.z = (v.z - mu) * inv * g.z + b.z;
  o.w = (v.w - mu) * inv * g.w + b.w;
  ((float4*)(y + (size_t)row * H_))[lane] = o;
}

// ---------------- sequential delta-rule scan ----------------
// 32 blocks: blockIdx.x = b*2 + mat. 256 threads; thread t owns M[row=t>>1][64*(t&1)..+63]
__global__ __launch_bounds__(256) void scan_kernel(const float* __restrict__ ksall,
                                                   const float* __restrict__ keall,
                                                   float* __restrict__ c) {
  int mat = blockIdx.x & 1;
  int b = blockIdx.x >> 1;
  const float* kp = (mat ? keall : ksall) + (size_t)b * L_ * HALF_;
  int tid = threadIdx.x;
  int i = tid >> 1;
  int half = tid & 1;

  __shared__ float kraw[HALF_];
  __shared__ float sred[2];

  float m[64];
#pragma unroll
  for (int g = 0; g < 64; g++) m[g] = 0.f;

  float cur = (tid < HALF_) ? kp[tid] : 0.f;

  for (int t = 0; t < L_ - 1; t++) {
    if (tid < HALF_) kraw[tid] = cur;
    __syncthreads();
    // prefetch next key (t+1 <= 511, valid; last prefetch is the final query)
    float nxt = (tid < HALF_) ? kp[(size_t)(t + 1) * HALF_ + tid] : 0.f;

    // ||k||^2 via per-wave butterfly over waves 0,1
    if (tid < HALF_) {
      float s = cur * cur;
#pragma unroll
      for (int off = 32; off >= 1; off >>= 1) s += __shfl_xor(s, off);
      if ((tid & 63) == 0) sred[tid >> 6] = s;
    }
    __syncthreads();
    float ss = sred[0] + sred[1];
    float inv = 1.f / fmaxf(sqrtf(ss), 1e-12f);

    const float4* k4 = (const float4*)kraw + half * 16;
    float4 kc[16];
    float partial = 0.f;
#pragma unroll
    for (int g = 0; g < 16; g++) {
      float4 kv = k4[g];
      kv.x *= inv; kv.y *= inv; kv.z *= inv; kv.w *= inv;
      kc[g] = kv;
      partial += m[4 * g + 0] * kv.x + m[4 * g + 1] * kv.y +
                 m[4 * g + 2] * kv.z + m[4 * g + 3] * kv.w;
    }
    float vp = partial + __shfl_xor(partial, 1);
    float d = kraw[i] - vp;
#pragma unroll
    for (int g = 0; g < 16; g++) {
      m[4 * g + 0] += d * kc[g].x;
      m[4 * g + 1] += d * kc[g].y;
      m[4 * g + 2] += d * kc[g].z;
      m[4 * g + 3] += d * kc[g].w;
    }
    cur = nxt;
    __syncthreads();
  }

  // final read with raw last-token key (no normalization)
  if (tid < HALF_) kraw[tid] = cur;
  __syncthreads();
  const float4* k4 = (const float4*)kraw + half * 16;
  float partial = 0.f;
#pragma unroll
  for (int g = 0; g < 16; g++) {
    float4 kv = k4[g];
    partial += m[4 * g + 0] * kv.x + m[4 * g + 1] * kv.y +
               m[4 * g + 2] * kv.z + m[4 * g + 3] * kv.w;
  }
  float vp = partial + __shfl_xor(partial, 1);
  if (half == 0) c[(size_t)b * H_ + mat * HALF_ + i] = vp;
}

// ---------------- r = c @ W_rp^T + b_rp ----------------
__global__ void rp_kernel(const float* __restrict__ c, const float* __restrict__ Wrp,
                          const float* __restrict__ brp, float* __restrict__ r) {
  int b = blockIdx.x;
  int n = threadIdx.x;  // 256
  __shared__ float cs[H_];
  cs[n] = c[(size_t)b * H_ + n];
  __syncthreads();
  const float4* w4 = (const float4*)(Wrp + (size_t)n * H_);
  const float4* c4 = (const float4*)cs;
  float acc = 0.f;
#pragma unroll 8
  for (int k = 0; k < H_ / 4; k++) {
    float4 w = w4[k], cc = c4[k];
    acc += w.x * cc.x + w.y * cc.y + w.z * cc.z + w.w * cc.w;
  }
  r[(size_t)b * H_ + n] = acc + brp[n];
}

// ---------------- out = r @ W_out^T + b_out ----------------
__global__ __launch_bounds__(256) void out_kernel(const float* __restrict__ r,
                                                  const float* __restrict__ Wout,
                                                  const float* __restrict__ bout,
                                                  float* __restrict__ out) {
  __shared__ float rs[B_ * H_];
  int tid = threadIdx.x;
#pragma unroll
  for (int q = 0; q < (B_ * H_) / 256; q++) rs[q * 256 + tid] = r[q * 256 + tid];
  __syncthreads();
  int v = blockIdx.x * 256 + tid;
  const float4* w4 = (const float4*)(Wout + (size_t)v * H_);
  float acc[B_];
#pragma unroll
  for (int b = 0; b < B_; b++) acc[b] = 0.f;
  for (int k = 0; k < H_ / 4; k++) {
    float4 w = w4[k];
#pragma unroll
    for (int b = 0; b < B_; b++) {
      float4 rr = *(const float4*)&rs[b * H_ + 4 * k];
      acc[b] += w.x * rr.x + w.y * rr.y + w.z * rr.z + w.w * rr.w;
    }
  }
  float bo = bout[v];
#pragma unroll
  for (int b = 0; b < B_; b++) out[(size_t)b * V_ + v] = acc[b] + bo;
}

extern "C" void kernel_launch(void* const* d_in, const int* in_sizes, int n_in,
                              void* d_out, int out_size, void* d_ws, size_t ws_size,
                              hipStream_t stream) {
  const int* seq = (const int*)d_in[0];
  const float* embed = (const float*)d_in[1];
  const float* W1 = (const float*)d_in[2];
  const float* b1 = (const float*)d_in[3];
  const float* W2 = (const float*)d_in[4];
  const float* b2 = (const float*)d_in[5];
  const float* gamma = (const float*)d_in[6];
  const float* beta = (const float*)d_in[7];
  const float* Wsem = (const float*)d_in[8];
  const float* Wepi = (const float*)d_in[9];
  const float* Wrp = (const float*)d_in[10];
  const float* brp = (const float*)d_in[11];
  const float* Wout = (const float*)d_in[12];
  const float* bout = (const float*)d_in[13];
  float* out = (float*)d_out;

  float* ws = (float*)d_ws;
  float* h = ws;                  // 8192*256 = 2,097,152 floats
  float* a1 = ws + 2097152;       // 8192*512 = 4,194,304 floats
  float* x = ws + 6291456;        // 8192*256
  float* hn = h;                  // LN output reuses h (h dead after GEMM2)
  float* ks = ws + 2097152;       // reuse a1 region (a1 dead after GEMM2)
  float* ke = ws + 3145728;
  float* c = ws + 4194304;        // 16*256
  float* r = ws + 4198400;        // 16*256

  // 1. gather
  gather_kernel<<<8192, 64, 0, stream>>>(seq, embed, h);
  // 2. a1 = relu(h @ W1^T + b1)   [8192,512]
  gemm_tn<true, true, false><<<dim3(8, 128), 256, 0, stream>>>(h, W1, b1, nullptr, a1, 8192, 512, 256);
  // 3. x = a1 @ W2^T + b2 + h     [8192,256]
  gemm_tn<false, true, true><<<dim3(4, 128), 256, 0, stream>>>(a1, W2, b2, h, x, 8192, 256, 512);
  // 4. hn = LayerNorm(x)
  ln_kernel<<<8192, 64, 0, stream>>>(x, gamma, beta, hn);
  // 5. ks = hn @ Wsem^T, ke = hn @ Wepi^T   [8192,128]
  gemm_tn<false, false, false><<<dim3(2, 128), 256, 0, stream>>>(hn, Wsem, nullptr, nullptr, ks, 8192, 128, 256);
  gemm_tn<false, false, false><<<dim3(2, 128), 256, 0, stream>>>(hn, Wepi, nullptr, nullptr, ke, 8192, 128, 256);
  // 6. sequential delta-rule scan -> c [16,256]
  scan_kernel<<<32, 256, 0, stream>>>(ks, ke, c);
  // 7. r = c @ Wrp^T + brp
  rp_kernel<<<16, 256, 0, stream>>>(c, Wrp, brp, r);
  // 8. out = r @ Wout^T + bout  [16,32000]
  out_kernel<<<125, 256, 0, stream>>>(r, Wout, bout, out);
}

// Round 2
// 340.465 us; speedup vs baseline: 2.5421x; 2.5421x over previous
//
#include <hip/hip_runtime.h>

#define B_ 16
#define L_ 512
#define H_ 256
#define V_ 32000
#define HALF_ 128

// ---------------- embedding gather ----------------
__global__ void gather_kernel(const int* __restrict__ seq, const float* __restrict__ embed,
                              float* __restrict__ h) {
  int token = blockIdx.x;
  int lane = threadIdx.x;            // 64 threads, float4 each -> 256 floats
  int row = seq[token];
  const float4* e4 = (const float4*)(embed + (size_t)row * H_);
  float4* h4 = (float4*)(h + (size_t)token * H_);
  h4[lane] = e4[lane];
}

// ---------------- fp32 TN GEMM: C[M,N] = act(A[M,K] @ B[N,K]^T + bias + R) ----------------
template <bool RELU, bool HASBIAS, bool HASRES>
__global__ __launch_bounds__(256) void gemm_tn(const float* __restrict__ A,
                                               const float* __restrict__ Bm,
                                               const float* __restrict__ bias,
                                               const float* __restrict__ Rm,
                                               float* __restrict__ C,
                                               int M, int N, int K) {
  __shared__ float As[16][68];
  __shared__ float Bs[16][68];
  int tid = threadIdx.x;
  int bm = blockIdx.y * 64, bn = blockIdx.x * 64;
  int tx = tid & 15, ty = tid >> 4;
  int lr = tid >> 2;          // 0..63
  int lk = (tid & 3) * 4;     // 0,4,8,12
  float acc[4][4];
#pragma unroll
  for (int rr = 0; rr < 4; rr++)
#pragma unroll
    for (int cc = 0; cc < 4; cc++) acc[rr][cc] = 0.f;

  const float* Aptr = A + (size_t)(bm + lr) * K + lk;
  const float* Bptr = Bm + (size_t)(bn + lr) * K + lk;

  for (int k0 = 0; k0 < K; k0 += 16) {
    float4 a4 = *(const float4*)(Aptr + k0);
    float4 b4 = *(const float4*)(Bptr + k0);
    __syncthreads();
    As[lk + 0][lr] = a4.x; As[lk + 1][lr] = a4.y; As[lk + 2][lr] = a4.z; As[lk + 3][lr] = a4.w;
    Bs[lk + 0][lr] = b4.x; Bs[lk + 1][lr] = b4.y; Bs[lk + 2][lr] = b4.z; Bs[lk + 3][lr] = b4.w;
    __syncthreads();
#pragma unroll
    for (int kk = 0; kk < 16; kk++) {
      float4 av = *(const float4*)&As[kk][ty * 4];
      float4 bv = *(const float4*)&Bs[kk][tx * 4];
      float ar[4] = {av.x, av.y, av.z, av.w};
      float br[4] = {bv.x, bv.y, bv.z, bv.w};
#pragma unroll
      for (int rr = 0; rr < 4; rr++)
#pragma unroll
        for (int cc = 0; cc < 4; cc++) acc[rr][cc] += ar[rr] * br[cc];
    }
  }

  int col = bn + tx * 4;
  float4 bb;
  if (HASBIAS) bb = *(const float4*)(bias + col);
  else { bb.x = bb.y = bb.z = bb.w = 0.f; }
#pragma unroll
  for (int rr = 0; rr < 4; rr++) {
    int row = bm + ty * 4 + rr;
    float4 o;
    o.x = acc[rr][0] + bb.x;
    o.y = acc[rr][1] + bb.y;
    o.z = acc[rr][2] + bb.z;
    o.w = acc[rr][3] + bb.w;
    if (HASRES) {
      float4 rv = *(const float4*)(Rm + (size_t)row * N + col);
      o.x += rv.x; o.y += rv.y; o.z += rv.z; o.w += rv.w;
    }
    if (RELU) {
      o.x = fmaxf(o.x, 0.f); o.y = fmaxf(o.y, 0.f);
      o.z = fmaxf(o.z, 0.f); o.w = fmaxf(o.w, 0.f);
    }
    *(float4*)(C + (size_t)row * N + col) = o;
  }
}

// ---------------- LayerNorm over H=256, one wave per row ----------------
__global__ void ln_kernel(const float* __restrict__ x, const float* __restrict__ gamma,
                          const float* __restrict__ beta, float* __restrict__ y) {
  int row = blockIdx.x;
  int lane = threadIdx.x;  // 64
  const float4* x4 = (const float4*)(x + (size_t)row * H_);
  float4 v = x4[lane];
  float s = v.x + v.y + v.z + v.w;
  float sq = v.x * v.x + v.y * v.y + v.z * v.z + v.w * v.w;
#pragma unroll
  for (int off = 32; off >= 1; off >>= 1) {
    s += __shfl_xor(s, off);
    sq += __shfl_xor(sq, off);
  }
  float mu = s * (1.f / H_);
  float var = sq * (1.f / H_) - mu * mu;
  float inv = rsqrtf(var + 1e-5f);
  float4 g = ((const float4*)gamma)[lane];
  float4 b = ((const float4*)beta)[lane];
  float4 o;
  o.x = (v.x - mu) * inv * g.x + b.x;
  o.y = (v.y - mu) * inv * g.y + b.y;
  o.z = (v.z - mu) * inv * g.z + b.z;
  o.w = (v.w - mu) * inv * g.w + b.w;
  ((float4*)(y + (size_t)row * H_))[lane] = o;
}

// ---------------- inv-norm precompute: inv[idxm*512+t] = 1/max(||k_t||,eps) ----------------
__global__ __launch_bounds__(256) void invnorm_kernel(const float* __restrict__ ks,
                                                      const float* __restrict__ ke,
                                                      float* __restrict__ inv) {
  int e = blockIdx.x * 4 + (threadIdx.x >> 6);  // one wave per (idxm,t)
  int lane = threadIdx.x & 63;
  int idxm = e >> 9;        // b*2+mat
  int t = e & 511;
  const float* kp = (idxm & 1 ? ke : ks) + (size_t)(idxm >> 1) * L_ * HALF_;
  float2 v = ((const float2*)(kp + (size_t)t * HALF_))[lane];
  float s = v.x * v.x + v.y * v.y;
#pragma unroll
  for (int off = 32; off >= 1; off >>= 1) s += __shfl_xor(s, off);
  if (lane == 0) inv[e] = 1.f / fmaxf(sqrtf(s), 1e-12f);
}

// ---------------- row-parallel delta-rule scan ----------------
// The recurrence is row-local: M[i] += (k_t[i] - M[i]. khat_t) * khat_t.
// 256 blocks x 256 threads: block = (idxm, rowgroup of 16 rows); 16 lanes/row, 8 cols/lane.
// Reductions are within aligned 16-lane groups -> pure DPP, no LDS, no barriers.
template <int CTRL>
__device__ __forceinline__ float dpp_xor_add(float x) {
  int y = __builtin_amdgcn_mov_dpp(__float_as_int(x), CTRL, 0xf, 0xf, true);
  return x + __int_as_float(y);
}

__global__ __launch_bounds__(256) void scan_kernel(const float* __restrict__ ksall,
                                                   const float* __restrict__ keall,
                                                   const float* __restrict__ invp,
                                                   float* __restrict__ c) {
  int bid = blockIdx.x;
  int rg = bid & 7;           // rowgroup 0..7 (16 rows each)
  int idxm = bid >> 3;        // 0..31 = b*2+mat
  int b = idxm >> 1, mat = idxm & 1;
  const float* kp = (mat ? keall : ksall) + (size_t)b * L_ * HALF_;
  const float* ivp = invp + (size_t)idxm * L_;

  int tid = threadIdx.x;
  int seg = tid & 15;         // 16 lanes per row
  int rlocal = tid >> 4;      // 0..15
  int r = rg * 16 + rlocal;   // global row of M
  int c0 = seg * 8;           // this lane's 8 columns

  float m0 = 0.f, m1 = 0.f, m2 = 0.f, m3 = 0.f, m4 = 0.f, m5 = 0.f, m6 = 0.f, m7 = 0.f;

  // preload t=0
  const float* k0p = kp;
  float4 ka = *(const float4*)(k0p + c0);
  float4 kb = *(const float4*)(k0p + c0 + 4);
  float kr = k0p[r];
  float iv = ivp[0];

  for (int t = 0; t < L_ - 1; t++) {
    // prefetch t+1 (t+1==511 is the final raw query; iv unused there)
    const float* np = kp + (size_t)(t + 1) * HALF_;
    float4 na = *(const float4*)(np + c0);
    float4 nb = *(const float4*)(np + c0 + 4);
    float nkr = np[r];
    float niv = (t < L_ - 2) ? ivp[t + 1] : 1.f;

    // p = dot(m_row, k_raw) over this lane's 8 cols
    float pa = m0 * ka.x + m1 * ka.y;
    float pb = m2 * ka.z + m3 * ka.w;
    float pc = m4 * kb.x + m5 * kb.y;
    float pd = m6 * kb.z + m7 * kb.w;
    float p = (pa + pb) + (pc + pd);
    // reduce across the 16 lanes of this row (xor1, xor2, xor4*, xor8*)
    p = dpp_xor_add<0xB1>(p);   // quad_perm(1,0,3,2)
    p = dpp_xor_add<0x4E>(p);   // quad_perm(2,3,0,1)
    p = dpp_xor_add<0x141>(p);  // row_half_mirror (xor7 ~ xor4 at quad granularity)
    p = dpp_xor_add<0x140>(p);  // row_mirror (xor15 ~ xor8 at oct granularity)

    float vp = p * iv;            // dot(m, khat)
    float s = (kr - vp) * iv;     // (k[r]-vp) scaled: m += s * k_raw == d * khat
    m0 += s * ka.x; m1 += s * ka.y; m2 += s * ka.z; m3 += s * ka.w;
    m4 += s * kb.x; m5 += s * kb.y; m6 += s * kb.z; m7 += s * kb.w;

    ka = na; kb = nb; kr = nkr; iv = niv;
  }

  // final read with raw last-token key
  float pa = m0 * ka.x + m1 * ka.y;
  float pb = m2 * ka.z + m3 * ka.w;
  float pc = m4 * kb.x + m5 * kb.y;
  float pd = m6 * kb.z + m7 * kb.w;
  float p = (pa + pb) + (pc + pd);
  p = dpp_xor_add<0xB1>(p);
  p = dpp_xor_add<0x4E>(p);
  p = dpp_xor_add<0x141>(p);
  p = dpp_xor_add<0x140>(p);
  if (seg == 0) c[(size_t)b * H_ + mat * HALF_ + r] = p;
}

// ---------------- r = c @ W_rp^T + b_rp ----------------
__global__ void rp_kernel(const float* __restrict__ c, const float* __restrict__ Wrp,
                          const float* __restrict__ brp, float* __restrict__ r) {
  int b = blockIdx.x;
  int n = threadIdx.x;  // 256
  __shared__ float cs[H_];
  cs[n] = c[(size_t)b * H_ + n];
  __syncthreads();
  const float4* w4 = (const float4*)(Wrp + (size_t)n * H_);
  const float4* c4 = (const float4*)cs;
  float acc = 0.f;
#pragma unroll 8
  for (int k = 0; k < H_ / 4; k++) {
    float4 w = w4[k], cc = c4[k];
    acc += w.x * cc.x + w.y * cc.y + w.z * cc.z + w.w * cc.w;
  }
  r[(size_t)b * H_ + n] = acc + brp[n];
}

// ---------------- out = r @ W_out^T + b_out ----------------
__global__ __launch_bounds__(256) void out_kernel(const float* __restrict__ r,
                                                  const float* __restrict__ Wout,
                                                  const float* __restrict__ bout,
                                                  float* __restrict__ out) {
  __shared__ float rs[B_ * H_];
  int tid = threadIdx.x;
#pragma unroll
  for (int q = 0; q < (B_ * H_) / 256; q++) rs[q * 256 + tid] = r[q * 256 + tid];
  __syncthreads();
  int v = blockIdx.x * 256 + tid;
  const float4* w4 = (const float4*)(Wout + (size_t)v * H_);
  float acc[B_];
#pragma unroll
  for (int b = 0; b < B_; b++) acc[b] = 0.f;
  for (int k = 0; k < H_ / 4; k++) {
    float4 w = w4[k];
#pragma unroll
    for (int b = 0; b < B_; b++) {
      float4 rr = *(const float4*)&rs[b * H_ + 4 * k];
      acc[b] += w.x * rr.x + w.y * rr.y + w.z * rr.z + w.w * rr.w;
    }
  }
  float bo = bout[v];
#pragma unroll
  for (int b = 0; b < B_; b++) out[(size_t)b * V_ + v] = acc[b] + bo;
}

extern "C" void kernel_launch(void* const* d_in, const int* in_sizes, int n_in,
                              void* d_out, int out_size, void* d_ws, size_t ws_size,
                              hipStream_t stream) {
  const int* seq = (const int*)d_in[0];
  const float* embed = (const float*)d_in[1];
  const float* W1 = (const float*)d_in[2];
  const float* b1 = (const float*)d_in[3];
  const float* W2 = (const float*)d_in[4];
  const float* b2 = (const float*)d_in[5];
  const float* gamma = (const float*)d_in[6];
  const float* beta = (const float*)d_in[7];
  const float* Wsem = (const float*)d_in[8];
  const float* Wepi = (const float*)d_in[9];
  const float* Wrp = (const float*)d_in[10];
  const float* brp = (const float*)d_in[11];
  const float* Wout = (const float*)d_in[12];
  const float* bout = (const float*)d_in[13];
  float* out = (float*)d_out;

  float* ws = (float*)d_ws;
  float* h = ws;                  // 8192*256 = 2,097,152 floats
  float* a1 = ws + 2097152;       // 8192*512 = 4,194,304 floats
  float* x = ws + 6291456;        // 8192*256
  float* hn = h;                  // LN output reuses h (h dead after GEMM2)
  float* ks = ws + 2097152;       // reuse a1 region (a1 dead after GEMM2)
  float* ke = ws + 3145728;
  float* c = ws + 4194304;        // 16*256
  float* r = ws + 4198400;        // 16*256
  float* inv = ws + 4202496;      // 32*512

  // 1. gather
  gather_kernel<<<8192, 64, 0, stream>>>(seq, embed, h);
  // 2. a1 = relu(h @ W1^T + b1)   [8192,512]
  gemm_tn<true, true, false><<<dim3(8, 128), 256, 0, stream>>>(h, W1, b1, nullptr, a1, 8192, 512, 256);
  // 3. x = a1 @ W2^T + b2 + h     [8192,256]
  gemm_tn<false, true, true><<<dim3(4, 128), 256, 0, stream>>>(a1, W2, b2, h, x, 8192, 256, 512);
  // 4. hn = LayerNorm(x)
  ln_kernel<<<8192, 64, 0, stream>>>(x, gamma, beta, hn);
  // 5. ks = hn @ Wsem^T, ke = hn @ Wepi^T   [8192,128]
  gemm_tn<false, false, false><<<dim3(2, 128), 256, 0, stream>>>(hn, Wsem, nullptr, nullptr, ks, 8192, 128, 256);
  gemm_tn<false, false, false><<<dim3(2, 128), 256, 0, stream>>>(hn, Wepi, nullptr, nullptr, ke, 8192, 128, 256);
  // 6. inv norms for all (b,mat,t)
  invnorm_kernel<<<4096, 256, 0, stream>>>(ks, ke, inv);
  // 7. row-parallel delta-rule scan -> c [16,256]
  scan_kernel<<<256, 256, 0, stream>>>(ks, ke, inv, c);
  // 8. r = c @ Wrp^T + brp
  rp_kernel<<<16, 256, 0, stream>>>(c, Wrp, brp, r);
  // 9. out = r @ Wout^T + bout  [16,32000]
  out_kernel<<<125, 256, 0, stream>>>(r, Wout, bout, out);
}

// Round 3
// 249.857 us; speedup vs baseline: 3.4640x; 1.3626x over previous
//
#include <hip/hip_runtime.h>

#define B_ 16
#define L_ 512
#define H_ 256
#define V_ 32000
#define HALF_ 128

typedef __attribute__((ext_vector_type(8))) short short8;
typedef __attribute__((ext_vector_type(4))) float floatx4;

__device__ __forceinline__ unsigned short f2bf(float x) {
  unsigned int u = __float_as_uint(x);
  unsigned int r = (u + 0x7FFFu + ((u >> 16) & 1u)) >> 16;
  return (unsigned short)r;
}

// ---------------- embedding gather: h fp32 + h bf16 ----------------
__global__ void gather_kernel(const int* __restrict__ seq, const float* __restrict__ embed,
                              float* __restrict__ h, unsigned short* __restrict__ hbf) {
  int token = blockIdx.x;
  int lane = threadIdx.x;  // 64 threads, float4 each
  int row = seq[token];
  float4 v = ((const float4*)(embed + (size_t)row * H_))[lane];
  ((float4*)(h + (size_t)token * H_))[lane] = v;
  ushort4 b;
  b.x = f2bf(v.x); b.y = f2bf(v.y); b.z = f2bf(v.z); b.w = f2bf(v.w);
  *(ushort4*)(hbf + (size_t)token * H_ + lane * 4) = b;
}

// ---------------- weight -> bf16 conversion (W1, W2, [Wsem;Wepi]) ----------------
__global__ void wconv_kernel(const float* __restrict__ W1, const float* __restrict__ W2,
                             const float* __restrict__ Ws, const float* __restrict__ We,
                             unsigned short* __restrict__ W1b, unsigned short* __restrict__ W2b,
                             unsigned short* __restrict__ Wcb) {
  int i = blockIdx.x * 256 + threadIdx.x;  // 0..327679
  if (i < 131072) W1b[i] = f2bf(W1[i]);
  else if (i < 262144) W2b[i - 131072] = f2bf(W2[i - 131072]);
  else if (i < 294912) Wcb[i - 262144] = f2bf(Ws[i - 262144]);
  else Wcb[i - 262144] = f2bf(We[i - 294912]);
}

// ---------------- bf16 MFMA GEMM: C[M,N] = act(A[M,K] @ B[N,K]^T + bias + Res) ----------------
// 128x128 tile, 4 waves (2x2 of 64x64), 16x16x32 bf16 MFMA. A,B bf16 row-major [*,K].
template <bool RELU, bool BIAS, bool RES, bool OUT_BF16>
__global__ __launch_bounds__(256) void gemm_mfma(const unsigned short* __restrict__ A,
                                                 const unsigned short* __restrict__ Bw,
                                                 const float* __restrict__ bias,
                                                 const float* __restrict__ Res,
                                                 float* __restrict__ Cf,
                                                 unsigned short* __restrict__ Cb,
                                                 int M, int N, int K) {
  __shared__ unsigned short As[128 * 40];  // row stride 40 bf16 (80B) to spread banks
  __shared__ unsigned short Bs[128 * 40];
  int tid = threadIdx.x;
  int wave = tid >> 6, lane = tid & 63;
  int wm = (wave >> 1) * 64, wn = (wave & 1) * 64;
  int quad = lane >> 4, l15 = lane & 15;
  int bm = blockIdx.y * 128, bn = blockIdx.x * 128;
  int sr = tid >> 2, sq = tid & 3;  // staging: row 0..63, 16B chunk 0..3

  floatx4 zero = {0.f, 0.f, 0.f, 0.f};
  floatx4 acc[4][4];
#pragma unroll
  for (int fi = 0; fi < 4; fi++)
#pragma unroll
    for (int fj = 0; fj < 4; fj++) acc[fi][fj] = zero;

  for (int k0 = 0; k0 < K; k0 += 32) {
    uint4 av0 = *(const uint4*)(A + (size_t)(bm + sr) * K + k0 + sq * 8);
    uint4 av1 = *(const uint4*)(A + (size_t)(bm + 64 + sr) * K + k0 + sq * 8);
    uint4 bv0 = *(const uint4*)(Bw + (size_t)(bn + sr) * K + k0 + sq * 8);
    uint4 bv1 = *(const uint4*)(Bw + (size_t)(bn + 64 + sr) * K + k0 + sq * 8);
    __syncthreads();
    *(uint4*)(As + sr * 40 + sq * 8) = av0;
    *(uint4*)(As + (64 + sr) * 40 + sq * 8) = av1;
    *(uint4*)(Bs + sr * 40 + sq * 8) = bv0;
    *(uint4*)(Bs + (64 + sr) * 40 + sq * 8) = bv1;
    __syncthreads();
    short8 af[4], bf[4];
#pragma unroll
    for (int f = 0; f < 4; f++) {
      af[f] = *(const short8*)(As + (wm + f * 16 + l15) * 40 + quad * 8);
      bf[f] = *(const short8*)(Bs + (wn + f * 16 + l15) * 40 + quad * 8);
    }
#pragma unroll
    for (int fi = 0; fi < 4; fi++)
#pragma unroll
      for (int fj = 0; fj < 4; fj++)
        acc[fi][fj] = __builtin_amdgcn_mfma_f32_16x16x32_bf16(af[fi], bf[fj], acc[fi][fj], 0, 0, 0);
  }

  // epilogue: D[row=(quad*4+reg), col=l15] per 16x16 frag
#pragma unroll
  for (int fi = 0; fi < 4; fi++) {
#pragma unroll
    for (int fj = 0; fj < 4; fj++) {
      int col = bn + wn + fj * 16 + l15;
      float bb = BIAS ? bias[col] : 0.f;
#pragma unroll
      for (int rg = 0; rg < 4; rg++) {
        int row = bm + wm + fi * 16 + quad * 4 + rg;
        float v = acc[fi][fj][rg] + bb;
        if (RES) v += Res[(size_t)row * N + col];
        if (RELU) v = fmaxf(v, 0.f);
        if (OUT_BF16) Cb[(size_t)row * N + col] = f2bf(v);
        else Cf[(size_t)row * N + col] = v;
      }
    }
  }
}

// ---------------- LayerNorm over H=256, one wave per row; bf16 output ----------------
__global__ void ln_kernel(const float* __restrict__ x, const float* __restrict__ gamma,
                          const float* __restrict__ beta, unsigned short* __restrict__ yb) {
  int row = blockIdx.x;
  int lane = threadIdx.x;  // 64
  float4 v = ((const float4*)(x + (size_t)row * H_))[lane];
  float s = v.x + v.y + v.z + v.w;
  float sq = v.x * v.x + v.y * v.y + v.z * v.z + v.w * v.w;
#pragma unroll
  for (int off = 32; off >= 1; off >>= 1) {
    s += __shfl_xor(s, off);
    sq += __shfl_xor(sq, off);
  }
  float mu = s * (1.f / H_);
  float var = sq * (1.f / H_) - mu * mu;
  float inv = rsqrtf(var + 1e-5f);
  float4 g = ((const float4*)gamma)[lane];
  float4 b = ((const float4*)beta)[lane];
  ushort4 o;
  o.x = f2bf((v.x - mu) * inv * g.x + b.x);
  o.y = f2bf((v.y - mu) * inv * g.y + b.y);
  o.z = f2bf((v.z - mu) * inv * g.z + b.z);
  o.w = f2bf((v.w - mu) * inv * g.w + b.w);
  *(ushort4*)(yb + (size_t)row * H_ + lane * 4) = o;
}

// ---------------- normalize keys -> bf16 khat[idxm][t][128] ----------------
__global__ __launch_bounds__(256) void normalize_kernel(const float* __restrict__ kcat,
                                                        unsigned short* __restrict__ khat) {
  int e = blockIdx.x * 4 + (threadIdx.x >> 6);  // e = idxm*512 + t
  int lane = threadIdx.x & 63;
  int idxm = e >> 9, t = e & 511;
  int b = idxm >> 1, mat = idxm & 1;
  const float* kp = kcat + ((size_t)b * L_ + t) * 256 + mat * 128;
  float2 v = ((const float2*)kp)[lane];
  float s = v.x * v.x + v.y * v.y;
#pragma unroll
  for (int off = 32; off >= 1; off >>= 1) s += __shfl_xor(s, off);
  float inv = 1.f / fmaxf(sqrtf(s), 1e-12f);
  ushort2 o;
  o.x = f2bf(v.x * inv);
  o.y = f2bf(v.y * inv);
  *(ushort2*)(khat + (size_t)e * HALF_ + lane * 2) = o;
}

// ---------------- row-parallel delta-rule scan, bf16 khat, 4-deep prefetch ----------------
template <int CTRL>
__device__ __forceinline__ float dpp_xor_add(float x) {
  int y = __builtin_amdgcn_mov_dpp(__float_as_int(x), CTRL, 0xf, 0xf, true);
  return x + __int_as_float(y);
}

#define BL_(u) __uint_as_float((u) << 16)
#define BH_(u) __uint_as_float((u) & 0xffff0000u)

#define SCAN_STEP(PK, PR)                                              \
  do {                                                                 \
    float k0 = BL_(PK.x), k1 = BH_(PK.x), k2 = BL_(PK.y), k3 = BH_(PK.y), \
          k4 = BL_(PK.z), k5 = BH_(PK.z), k6 = BL_(PK.w), k7 = BH_(PK.w); \
    float pa = m[0] * k0 + m[1] * k1, pb = m[2] * k2 + m[3] * k3,      \
          pc = m[4] * k4 + m[5] * k5, pd = m[6] * k6 + m[7] * k7;      \
    float p = (pa + pb) + (pc + pd);                                   \
    p = dpp_xor_add<0xB1>(p);                                          \
    p = dpp_xor_add<0x4E>(p);                                          \
    p = dpp_xor_add<0x141>(p);                                         \
    p = dpp_xor_add<0x140>(p);                                         \
    float sS = PR - p;                                                 \
    m[0] += sS * k0; m[1] += sS * k1; m[2] += sS * k2; m[3] += sS * k3; \
    m[4] += sS * k4; m[5] += sS * k5; m[6] += sS * k6; m[7] += sS * k7; \
  } while (0)

__global__ __launch_bounds__(256) void scan_kernel(const float* __restrict__ kcat,
                                                   const unsigned short* __restrict__ khat,
                                                   float* __restrict__ c) {
  int bid = blockIdx.x;
  int idxm = bid & 31;  // XCD swizzle: all 8 blocks of one idxm -> same XCD L2
  int rg = bid >> 5;
  int b = idxm >> 1, mat = idxm & 1;
  const unsigned short* kh = khat + (size_t)idxm * L_ * HALF_;
  const float* kbase = kcat + (size_t)b * L_ * 256 + mat * HALF_;

  int tid = threadIdx.x;
  int seg = tid & 15;       // 16 lanes per row
  int rl = tid >> 4;        // 0..15
  int r = rg * 16 + rl;     // row of M
  int c0 = seg * 8;         // 8 cols per lane
  const float* krow = kbase + r;

  float m[8];
#pragma unroll
  for (int g = 0; g < 8; g++) m[g] = 0.f;

  uint4 pk[4];
  float pr[4];
#pragma unroll
  for (int u = 0; u < 4; u++) {
    pk[u] = *(const uint4*)(kh + (size_t)u * HALF_ + c0);
    pr[u] = krow[(size_t)u * 256];
  }

  for (int t = 0; t < 508; t += 4) {
#pragma unroll
    for (int u = 0; u < 4; u++) {
      int tt = t + u;
      uint4 nk = *(const uint4*)(kh + (size_t)(tt + 4) * HALF_ + c0);
      float nr = krow[(size_t)(tt + 4) * 256];
      SCAN_STEP(pk[u], pr[u]);
      pk[u] = nk;
      pr[u] = nr;
    }
  }
  SCAN_STEP(pk[0], pr[0]);
  SCAN_STEP(pk[1], pr[1]);
  SCAN_STEP(pk[2], pr[2]);

  // final read with raw fp32 last-token key
  float4 qa = *(const float4*)(kbase + (size_t)511 * 256 + c0);
  float4 qb = *(const float4*)(kbase + (size_t)511 * 256 + c0 + 4);
  float pa = m[0] * qa.x + m[1] * qa.y, pb2 = m[2] * qa.z + m[3] * qa.w;
  float pc = m[4] * qb.x + m[5] * qb.y, pd = m[6] * qb.z + m[7] * qb.w;
  float p = (pa + pb2) + (pc + pd);
  p = dpp_xor_add<0xB1>(p);
  p = dpp_xor_add<0x4E>(p);
  p = dpp_xor_add<0x141>(p);
  p = dpp_xor_add<0x140>(p);
  if (seg == 0) c[(size_t)b * H_ + mat * HALF_ + r] = p;
}

// ---------------- r = c @ W_rp^T + b_rp ----------------
__global__ void rp_kernel(const float* __restrict__ c, const float* __restrict__ Wrp,
                          const float* __restrict__ brp, float* __restrict__ r) {
  int b = blockIdx.x;
  int n = threadIdx.x;  // 256
  __shared__ float cs[H_];
  cs[n] = c[(size_t)b * H_ + n];
  __syncthreads();
  const float4* w4 = (const float4*)(Wrp + (size_t)n * H_);
  const float4* c4 = (const float4*)cs;
  float acc = 0.f;
#pragma unroll 8
  for (int k = 0; k < H_ / 4; k++) {
    float4 w = w4[k], cc = c4[k];
    acc += w.x * cc.x + w.y * cc.y + w.z * cc.z + w.w * cc.w;
  }
  r[(size_t)b * H_ + n] = acc + brp[n];
}

// ---------------- out = r @ W_out^T + b_out ----------------
__global__ __launch_bounds__(256) void out_kernel(const float* __restrict__ r,
                                                  const float* __restrict__ Wout,
                                                  const float* __restrict__ bout,
                                                  float* __restrict__ out) {
  __shared__ float rs[B_ * H_];
  int tid = threadIdx.x;
#pragma unroll
  for (int q = 0; q < (B_ * H_) / 256; q++) rs[q * 256 + tid] = r[q * 256 + tid];
  __syncthreads();
  int v = blockIdx.x * 256 + tid;
  const float4* w4 = (const float4*)(Wout + (size_t)v * H_);
  float acc[B_];
#pragma unroll
  for (int b = 0; b < B_; b++) acc[b] = 0.f;
  for (int k = 0; k < H_ / 4; k++) {
    float4 w = w4[k];
#pragma unroll
    for (int b = 0; b < B_; b++) {
      float4 rr = *(const float4*)&rs[b * H_ + 4 * k];
      acc[b] += w.x * rr.x + w.y * rr.y + w.z * rr.z + w.w * rr.w;
    }
  }
  float bo = bout[v];
#pragma unroll
  for (int b = 0; b < B_; b++) out[(size_t)b * V_ + v] = acc[b] + bo;
}

extern "C" void kernel_launch(void* const* d_in, const int* in_sizes, int n_in,
                              void* d_out, int out_size, void* d_ws, size_t ws_size,
                              hipStream_t stream) {
  const int* seq = (const int*)d_in[0];
  const float* embed = (const float*)d_in[1];
  const float* W1 = (const float*)d_in[2];
  const float* b1 = (const float*)d_in[3];
  const float* W2 = (const float*)d_in[4];
  const float* b2 = (const float*)d_in[5];
  const float* gamma = (const float*)d_in[6];
  const float* beta = (const float*)d_in[7];
  const float* Wsem = (const float*)d_in[8];
  const float* Wepi = (const float*)d_in[9];
  const float* Wrp = (const float*)d_in[10];
  const float* brp = (const float*)d_in[11];
  const float* Wout = (const float*)d_in[12];
  const float* bout = (const float*)d_in[13];
  float* out = (float*)d_out;

  float* ws = (float*)d_ws;
  // float-slot offsets
  float* h = ws;                                   // [8192,256] fp32; x written in-place
  float* x = h;
  float* kcat = ws + 2097152;                      // [8192,256] fp32 (a1b region first)
  unsigned short* a1b = (unsigned short*)kcat;     // [8192,512] bf16 (dead before kcat written)
  unsigned short* hbf = (unsigned short*)(ws + 4194304);   // [8192,256] bf16
  unsigned short* hnb = (unsigned short*)(ws + 5242880);   // [8192,256] bf16
  unsigned short* khat = (unsigned short*)(ws + 6291456);  // [32,512,128] bf16
  unsigned short* W1b = (unsigned short*)(ws + 7340032);   // 131072 bf16
  unsigned short* W2b = (unsigned short*)(ws + 7405568);   // 131072 bf16
  unsigned short* Wcb = (unsigned short*)(ws + 7471104);   // 65536 bf16 ([Wsem;Wepi])
  float* c = ws + 7503872;                          // [16,256]
  float* r = ws + 7508000;                          // [16,256] (aligned region)

  // 1. gather (fp32 + bf16)
  gather_kernel<<<8192, 64, 0, stream>>>(seq, embed, h, hbf);
  // 2. weight conversion
  wconv_kernel<<<1280, 256, 0, stream>>>(W1, W2, Wsem, Wepi, W1b, W2b, Wcb);
  // 3. a1 = relu(h @ W1^T + b1) -> bf16  [8192,512]
  gemm_mfma<true, true, false, true><<<dim3(4, 64), 256, 0, stream>>>(
      hbf, W1b, b1, nullptr, nullptr, a1b, 8192, 512, 256);
  // 4. x = a1 @ W2^T + b2 + h -> fp32 (in-place over h)  [8192,256]
  gemm_mfma<false, true, true, false><<<dim3(2, 64), 256, 0, stream>>>(
      a1b, W2b, b2, h, x, nullptr, 8192, 256, 512);
  // 5. hn = LayerNorm(x) -> bf16
  ln_kernel<<<8192, 64, 0, stream>>>(x, gamma, beta, hnb);
  // 6. kcat = hn @ [Wsem;Wepi]^T -> fp32  [8192,256]
  gemm_mfma<false, false, false, false><<<dim3(2, 64), 256, 0, stream>>>(
      hnb, Wcb, nullptr, nullptr, kcat, nullptr, 8192, 256, 256);
  // 7. khat = normalize(k) -> bf16
  normalize_kernel<<<4096, 256, 0, stream>>>(kcat, khat);
  // 8. delta-rule scan -> c [16,256]
  scan_kernel<<<256, 256, 0, stream>>>(kcat, khat, c);
  // 9. r = c @ Wrp^T + brp
  rp_kernel<<<16, 256, 0, stream>>>(c, Wrp, brp, r);
  // 10. out = r @ Wout^T + bout  [16,32000]
  out_kernel<<<125, 256, 0, stream>>>(r, Wout, bout, out);
}